// Round 5
// baseline (161.656 us; speedup 1.0000x reference)
//
#include <hip/hip_runtime.h>
#include <math.h>

constexpr int NROW = 8192;
constexpr int FD   = 256;
constexpr int NZ   = 16;

typedef unsigned short u16;
typedef __attribute__((ext_vector_type(8))) short short8;   // bf16 x8 (4 VGPR)
typedef __attribute__((ext_vector_type(4))) float f32x4;    // acc

// ws layout (bytes):
//   0        scal[8]             (scal2 = 2 floats at +128)
//   2048     gcnt u32[16]        (gram tile counters, zeroed by k_norm)
//   4096     fpart[2048]         (8 KB)
//   12288    nrm0[8192]          (32 KB)
//   45056    nrm1[8192]          (32 KB)
//   77824    f0[8192]            (32 KB)
//   110592   fpart1[512]         (2 KB)
//   112640   svec[256]
//   113664   vvec[256]
//   114688   cpart2[16][256]     (16 KB)
//   131072   cpart[256][256]     (256 KB)
//   393216   cpart1[512][256]    (512 KB)
//   917504   wpart1[512][256]    (512 KB)
//   1966080  Gbf u16[256][256]   (128 KB)
//   2097152  Rbf u16[8192][256]  (4 MB)
//   6291456  Rt  u16[256][8192]  (4 MB)
//   10485760 Gp  f32[16][256][256] (4 MB)
//   14680064 emb f32[8192][256]  (8 MB)
//   23068672 u[8192]             (32 KB)

__device__ __forceinline__ float f_of(float nj, float A, float B, float AB) {
    float inner = AB * nj;
    return A - (inner <= 0.f ? inner : 0.f) * B;
}
__device__ __forceinline__ float wred(float s) {
    #pragma unroll
    for (int off = 32; off; off >>= 1) s += __shfl_xor(s, off);
    return s;
}
__device__ __forceinline__ float dot4(float4 a, float4 b) {
    return a.x*b.x + a.y*b.y + a.z*b.z + a.w*b.w;
}
__device__ __forceinline__ u16 f2bf(float x) {   // RNE fp32 -> bf16
    unsigned int u = __float_as_uint(x);
    u = (u + 0x7FFFu + ((u >> 16) & 1u)) >> 16;
    return (u16)u;
}

// one wave per row: nrm0[j] = ||row||^2 ; block partial -> fpart[2048]
// block 0 also zeroes the gram tile counters for this iteration.
__global__ void k_norm(const float* __restrict__ in, float* __restrict__ nrm,
                       float* __restrict__ fpart, unsigned* __restrict__ gcnt) {
    __shared__ float bs[4];
    if (blockIdx.x == 0 && threadIdx.x < 16) gcnt[threadIdx.x] = 0u;
    int wave = threadIdx.x >> 6, lane = threadIdx.x & 63;
    int row = blockIdx.x * 4 + wave;
    const float4 v = *(const float4*)&in[(size_t)row * FD + lane * 4];
    float s = wred(dot4(v, v));
    if (lane == 0) { nrm[row] = s; bs[wave] = s; }
    __syncthreads();
    if (threadIdx.x == 0) fpart[blockIdx.x] = bs[0] + bs[1] + bs[2] + bs[3];
}

// prep: per-block scalar derivation, then R = f0*X bf16 row-major (Rbf) +
// transposed (Rt) + colsum partials + f0 array. 256 blocks x 32 rows (full GPU).
__global__ void __launch_bounds__(256, 2)
k_prep(const float* __restrict__ X, const float* __restrict__ nrm0,
       const float* __restrict__ fpart, const float* __restrict__ linear,
       const float* __restrict__ dirv, const float* __restrict__ feat,
       float* __restrict__ scal, float* __restrict__ f0,
       u16* __restrict__ Rbf, u16* __restrict__ Rt, float* __restrict__ cpart) {
    __shared__ u16 T[32][264];
    __shared__ float cred[4][256];
    __shared__ float l[256];
    __shared__ float ff[32];
    __shared__ float sdot[4];
    const int tid = threadIdx.x;
    const int r0 = blockIdx.x * 32;
    if (tid < 64) {
        for (int i = 0; i < 2; ++i) {
            float pa = 0.f, pb = 0.f;
            for (int k = tid; k < FD; k += 64) {
                float ll = linear[i*FD + k];
                pa += feat[i*FD + k] * ll;
                pb += dirv[i*FD + k] * ll;
            }
            pa = wred(pa); pb = wred(pb);
            if (tid == 0) { sdot[i] = pa; sdot[2 + i] = pb; }
        }
    }
    float s = 0.f;
    #pragma unroll
    for (int k = 0; k < 8; ++k) s += fpart[tid + k * 256];
    l[tid] = s;
    __syncthreads();
    for (int off = 128; off; off >>= 1) {
        if (tid < off) l[tid] += l[tid + off];
        __syncthreads();
    }
    const float F2 = l[0];
    const float a = sdot[0], b = sdot[2];
    const float sb = (b > 0.f) ? 1.f : ((b < 0.f) ? -1.f : 0.f);
    const float B = sb / sqrtf(F2);
    const float A = a, AB = a * B;
    if (blockIdx.x == 0 && tid == 0) {
        scal[0] = sdot[0]; scal[1] = sdot[1]; scal[2] = sdot[2]; scal[3] = sdot[3];
        scal[4] = A; scal[5] = B; scal[6] = AB; scal[7] = F2;
    }
    if (tid < 32) {
        float f = f_of(nrm0[r0 + tid], A, B, AB);
        ff[tid] = f;
        f0[r0 + tid] = f;
    }
    __syncthreads();
    const int cg0 = (tid & 63) * 4;
    const int rg = tid >> 6;
    float4 csum = make_float4(0.f, 0.f, 0.f, 0.f);
    #pragma unroll
    for (int i = 0; i < 8; ++i) {
        int row = rg * 8 + i;
        float4 v = *(const float4*)&X[(size_t)(r0 + row) * FD + cg0];
        float f = ff[row];
        v.x *= f; v.y *= f; v.z *= f; v.w *= f;
        csum.x += v.x; csum.y += v.y; csum.z += v.z; csum.w += v.w;
        unsigned lo = (unsigned)f2bf(v.x) | ((unsigned)f2bf(v.y) << 16);
        unsigned hi = (unsigned)f2bf(v.z) | ((unsigned)f2bf(v.w) << 16);
        uint2 pk = make_uint2(lo, hi);
        *(uint2*)&Rbf[(size_t)(r0 + row) * FD + cg0] = pk;
        *(uint2*)&T[row][cg0] = pk;
    }
    *(float4*)&cred[rg][cg0] = csum;
    __syncthreads();
    cpart[(size_t)blockIdx.x * FD + tid] =
        cred[0][tid] + cred[1][tid] + cred[2][tid] + cred[3][tid];
    const int c = tid;
    #pragma unroll
    for (int ch = 0; ch < 4; ++ch) {
        unsigned w0 = (unsigned)T[ch*8+0][c] | ((unsigned)T[ch*8+1][c] << 16);
        unsigned w1 = (unsigned)T[ch*8+2][c] | ((unsigned)T[ch*8+3][c] << 16);
        unsigned w2 = (unsigned)T[ch*8+4][c] | ((unsigned)T[ch*8+5][c] << 16);
        unsigned w3 = (unsigned)T[ch*8+6][c] | ((unsigned)T[ch*8+7][c] << 16);
        uint4 o = make_uint4(w0, w1, w2, w3);
        *(uint4*)&Rt[(size_t)c * NROW + r0 + ch * 8] = o;
    }
}

// Gram partials via MFMA (proven structure): grid (4,4,16); block = 4 waves,
// each a 32x32 quadrant, K=512 per z. The 16th (last) arriver per (bi,bj)
// tile reduces its 16 z-slices -> Gbf (same z order as old k_gred => bit-
// identical) and does that tile's cpart -> cpart2 fold.
__global__ void __launch_bounds__(256, 2)
k_gram(const u16* __restrict__ Rt, float* __restrict__ Gp,
       u16* __restrict__ Gbf, const float* __restrict__ cpart,
       float* __restrict__ cpart2, unsigned* __restrict__ gcnt) {
    const int bi = blockIdx.x, bj = blockIdx.y, z = blockIdx.z;
    const int tid = threadIdx.x, w = tid >> 6, lane = tid & 63;
    const int l15 = lane & 15, quad = lane >> 4;
    const int m0 = bi * 64 + (w & 1) * 32;
    const int n0 = bj * 64 + (w >> 1) * 32;
    const size_t kbase = (size_t)z * 512 + quad * 8;
    const u16* am0 = Rt + (size_t)(m0 + l15) * NROW + kbase;
    const u16* am1 = am0 + (size_t)16 * NROW;
    const u16* bn0 = Rt + (size_t)(n0 + l15) * NROW + kbase;
    const u16* bn1 = bn0 + (size_t)16 * NROW;
    f32x4 acc[2][2] = {};
    #pragma unroll
    for (int s = 0; s < 16; ++s) {
        int ko = s * 32;
        short8 a0 = *(const short8*)(am0 + ko);
        short8 a1 = *(const short8*)(am1 + ko);
        short8 b0 = *(const short8*)(bn0 + ko);
        short8 b1 = *(const short8*)(bn1 + ko);
        acc[0][0] = __builtin_amdgcn_mfma_f32_16x16x32_bf16(a0, b0, acc[0][0], 0, 0, 0);
        acc[0][1] = __builtin_amdgcn_mfma_f32_16x16x32_bf16(a0, b1, acc[0][1], 0, 0, 0);
        acc[1][0] = __builtin_amdgcn_mfma_f32_16x16x32_bf16(a1, b0, acc[1][0], 0, 0, 0);
        acc[1][1] = __builtin_amdgcn_mfma_f32_16x16x32_bf16(a1, b1, acc[1][1], 0, 0, 0);
    }
    float* gz = Gp + (size_t)z * (FD * FD);
    #pragma unroll
    for (int mi = 0; mi < 2; ++mi)
        #pragma unroll
        for (int ni = 0; ni < 2; ++ni)
            #pragma unroll
            for (int r = 0; r < 4; ++r)
                gz[(size_t)(m0 + mi*16 + quad*4 + r) * FD + n0 + ni*16 + l15] =
                    acc[mi][ni][r];
    // ---- last-arriver epilogue (replaces k_gred) ----
    __threadfence();                      // release our Gp slice
    __shared__ unsigned done;
    if (tid == 0) done = atomicAdd(&gcnt[bi * 4 + bj], 1u);
    __syncthreads();
    if (done == NZ - 1) {
        __threadfence();                  // acquire other blocks' slices
        const int tile = bi * 4 + bj;
        const int tm0 = bi * 64, tn0 = bj * 64;
        #pragma unroll
        for (int e = 0; e < 16; ++e) {
            int idx = e * 256 + tid;
            int r = idx >> 6, c = idx & 63;
            size_t off = (size_t)(tm0 + r) * FD + tn0 + c;
            float s = 0.f;
            #pragma unroll
            for (int zz = 0; zz < NZ; ++zz) s += Gp[(size_t)zz * (FD * FD) + off];
            Gbf[off] = f2bf(s);
        }
        float csv = 0.f;
        #pragma unroll
        for (int k = 0; k < 16; ++k)
            csv += cpart[(size_t)(tile * 16 + k) * FD + tid];
        cpart2[(size_t)tile * FD + tid] = csv;
    }
}

// apply via MFMA; 512 blocks x 16 rows (2 blocks/CU). fp32 epilogue ->
// emb/nrm1/fpart1[512]/cpart1[512]/wpart1[512].
__global__ void __launch_bounds__(256, 2)
k_apply(const float* __restrict__ X, const u16* __restrict__ Rbf,
        const u16* __restrict__ Gbf, const float* __restrict__ f0,
        const float* __restrict__ cpart2, float* __restrict__ emb,
        float* __restrict__ nrm1, float* __restrict__ fpart1,
        float* __restrict__ cpart1, float* __restrict__ wpart1) {
    __shared__ float Sl[16][260];
    __shared__ float csh[FD];
    __shared__ float u0s[16], ffs[16], nrs[16];
    __shared__ float nw16[16][16];
    const int tid = threadIdx.x, w = tid >> 6, lane = tid & 63;
    const int l15 = lane & 15, quad = lane >> 4;
    const int r0 = blockIdx.x * 16;

    {
        float s = 0.f;
        #pragma unroll
        for (int g = 0; g < 16; ++g) s += cpart2[(size_t)g * FD + tid];
        csh[tid] = s;
    }
    if (tid < 16) ffs[tid] = f0[r0 + tid];
    __syncthreads();
    #pragma unroll
    for (int jj = 0; jj < 4; ++jj) {
        int row = w * 4 + jj;
        float4 xv = *(const float4*)&X[(size_t)(r0 + row) * FD + lane * 4];
        float4 cv = *(const float4*)&csh[lane * 4];
        float t = wred(dot4(xv, cv));
        if (lane == 0) u0s[row] = ffs[row] * t;
    }
    const u16* ap = Rbf + (size_t)(r0 + l15) * FD + quad * 8;
    const int n0w = w * 64;
    const u16* bp = Gbf + (size_t)(n0w + l15) * FD + quad * 8;
    f32x4 acc[4] = {};
    #pragma unroll
    for (int s = 0; s < 8; ++s) {
        int ko = s * 32;
        short8 a0 = *(const short8*)(ap + ko);
        short8 b0 = *(const short8*)(bp + ko);
        short8 b1 = *(const short8*)(bp + 16 * FD + ko);
        short8 b2 = *(const short8*)(bp + 32 * FD + ko);
        short8 b3 = *(const short8*)(bp + 48 * FD + ko);
        acc[0] = __builtin_amdgcn_mfma_f32_16x16x32_bf16(a0, b0, acc[0], 0, 0, 0);
        acc[1] = __builtin_amdgcn_mfma_f32_16x16x32_bf16(a0, b1, acc[1], 0, 0, 0);
        acc[2] = __builtin_amdgcn_mfma_f32_16x16x32_bf16(a0, b2, acc[2], 0, 0, 0);
        acc[3] = __builtin_amdgcn_mfma_f32_16x16x32_bf16(a0, b3, acc[3], 0, 0, 0);
    }
    #pragma unroll
    for (int ni = 0; ni < 4; ++ni)
        #pragma unroll
        for (int r = 0; r < 4; ++r)
            Sl[quad*4 + r][n0w + ni*16 + l15] = acc[ni][r];
    __syncthreads();
    const float invN = 1.0f / NROW;
    float er[16];
    float csum = 0.f;
    #pragma unroll
    for (int j = 0; j < 16; ++j) {
        float x = X[(size_t)(r0 + j) * FD + tid];
        float rv = ffs[j] * x;
        float e = rv + (Sl[j][tid] - u0s[j] * rv) * invN;
        emb[(size_t)(r0 + j) * FD + tid] = e;
        er[j] = e;
        csum += e;
        Sl[j][tid] = e * e;
    }
    __syncthreads();
    {
        int row = tid & 15, q = tid >> 4;
        float pn = 0.f;
        #pragma unroll
        for (int i = 0; i < 16; ++i) pn += Sl[row][q * 16 + i];
        nw16[row][q] = pn;
    }
    __syncthreads();
    if (tid < 16) {
        float nn = 0.f;
        #pragma unroll
        for (int q = 0; q < 16; ++q) nn += nw16[tid][q];
        nrm1[r0 + tid] = nn;
        nrs[tid] = nn;
    }
    __syncthreads();
    float wsum = 0.f;
    #pragma unroll
    for (int j = 0; j < 16; ++j) wsum += nrs[j] * er[j];
    cpart1[(size_t)blockIdx.x * FD + tid] = csum;
    wpart1[(size_t)blockIdx.x * FD + tid] = wsum;
    if (tid == 0) {
        float fp = 0.f;
        #pragma unroll
        for (int j = 0; j < 16; ++j) fp += nrs[j];
        fpart1[blockIdx.x] = fp;
    }
}

// depth-1 scalars from fpart1[512]
__device__ __forceinline__ void red1_scal(const float* fpart1, const float* scal,
                                          float* l, float& A, float& B, float& AB,
                                          float& kap) {
    int tid = threadIdx.x;
    l[tid] = fpart1[tid] + fpart1[tid + 256];
    __syncthreads();
    for (int off = 128; off; off >>= 1) {
        if (tid < off) l[tid] += l[tid + off];
        __syncthreads();
    }
    float F2 = l[0];
    float a = scal[1], b = scal[3];
    float sb = (b > 0.f) ? 1.f : ((b < 0.f) ? -1.f : 0.f);
    B = sb / sqrtf(F2);
    A = a; AB = a * B;
    kap = (AB <= 0.f) ? AB * B : 0.f;
    __syncthreads();
}

// svec[col] = A1 * sum_b cpart1[b][col] - kappa * sum_b wpart1[b][col]
// block 0 publishes (A1, kap) to scal2; block 1 zeroes vvec for k_uv atomics.
__global__ void k_sv(const float* __restrict__ fpart1, const float* __restrict__ scal,
                     const float* __restrict__ cpart1, const float* __restrict__ wpart1,
                     float* __restrict__ svec, float* __restrict__ scal2,
                     float* __restrict__ vvec) {
    __shared__ float l[256];
    if (blockIdx.x == 1) vvec[threadIdx.x] = 0.f;
    float A1, B1, AB1, kap;
    red1_scal(fpart1, scal, l, A1, B1, AB1, kap);
    int tid = threadIdx.x;
    int col = blockIdx.x * 4 + (tid >> 6);
    int lane = tid & 63;
    float cs = 0.f, wsm = 0.f;
    #pragma unroll
    for (int b = lane; b < 512; b += 64) {
        cs  += cpart1[(size_t)b * FD + col];
        wsm += wpart1[(size_t)b * FD + col];
    }
    #pragma unroll
    for (int off = 32; off; off >>= 1) {
        cs  += __shfl_down(cs, off);
        wsm += __shfl_down(wsm, off);
    }
    if (lane == 0) svec[col] = A1 * cs - kap * wsm;
    if (blockIdx.x == 0 && tid == 0) { scal2[0] = A1; scal2[1] = kap; }
}

// fused uv: single emb pass (er regs); u[row] = f1 (emb_row . s);
// per-block v-partial atomically accumulated into vvec (zeroed by k_sv).
__global__ void __launch_bounds__(256)
k_uv(const float* __restrict__ emb, const float* __restrict__ nrm1,
     const float* __restrict__ scal2, const float* __restrict__ svec,
     float* __restrict__ u, float* __restrict__ vvec) {
    __shared__ float red[4][16];
    __shared__ float uf[16];
    const int tid = threadIdx.x, w = tid >> 6, lane = tid & 63;
    const int r0 = blockIdx.x * 16;
    const float A1 = scal2[0], kap = scal2[1];
    const float svt = svec[tid];
    float er[16];
    #pragma unroll
    for (int j = 0; j < 16; ++j)
        er[j] = emb[(size_t)(r0 + j) * FD + tid];
    #pragma unroll
    for (int j = 0; j < 16; ++j) {
        float v = wred(er[j] * svt);
        if (lane == 0) red[w][j] = v;
    }
    __syncthreads();
    if (tid < 16) {
        float s = red[0][tid] + red[1][tid] + red[2][tid] + red[3][tid];
        float f = A1 - kap * nrm1[r0 + tid];
        float uj = f * s;
        u[r0 + tid] = uj;
        uf[tid] = uj * f;
    }
    __syncthreads();
    float vp = 0.f;
    #pragma unroll
    for (int j = 0; j < 16; ++j) vp += uf[j] * er[j];
    atomicAdd(&vvec[tid], vp);
}

// out[row] = (u + (f1*(emb_row . v) - u^2)/N)/N
__global__ void k_out(const float* __restrict__ emb, const float* __restrict__ nrm1,
                      const float* __restrict__ scal2, const float* __restrict__ vvec,
                      const float* __restrict__ u, float* __restrict__ out) {
    __shared__ float vsh[FD];
    const int tid = threadIdx.x;
    const int r0 = blockIdx.x * 16;
    const float A1 = scal2[0], kap = scal2[1];
    vsh[tid] = vvec[tid];
    __syncthreads();
    const int wave = tid >> 6, lane = tid & 63;
    const float invN = 1.0f / NROW;
    float4 vv = *(const float4*)&vsh[lane*4];
    #pragma unroll
    for (int jj = 0; jj < 4; ++jj) {
        int row = r0 + wave * 4 + jj;
        float4 ev = *(const float4*)&emb[(size_t)row * FD + lane*4];
        float s = wred(dot4(ev, vv));
        if (lane == 0 && row < NROW - 1) {
            float f = A1 - kap * nrm1[row];
            float uj = u[row];
            out[row] = (uj + (f * s - uj * uj) * invN) * invN;
        }
    }
}

extern "C" void kernel_launch(void* const* d_in, const int* in_sizes, int n_in,
                              void* d_out, int out_size, void* d_ws, size_t ws_size,
                              hipStream_t stream) {
    const float* X      = (const float*)d_in[0];
    // d_in[1] = coefs (unused by the reference forward)
    const float* linear = (const float*)d_in[2];
    const float* dirv   = (const float*)d_in[3];
    const float* feat   = (const float*)d_in[4];
    float* out = (float*)d_out;

    char* ws = (char*)d_ws;
    float*    scal   = (float*)   (ws + 0);
    float*    scal2  = (float*)   (ws + 128);
    unsigned* gcnt   = (unsigned*)(ws + 2048);
    float*    fpart  = (float*)   (ws + 4096);
    float*    nrm0   = (float*)   (ws + 12288);
    float*    nrm1   = (float*)   (ws + 45056);
    float*    f0     = (float*)   (ws + 77824);
    float*    fpart1 = (float*)   (ws + 110592);
    float*    svec   = (float*)   (ws + 112640);
    float*    vvec   = (float*)   (ws + 113664);
    float*    cpart2 = (float*)   (ws + 114688);
    float*    cpart  = (float*)   (ws + 131072);
    float*    cpart1 = (float*)   (ws + 393216);
    float*    wpart1 = (float*)   (ws + 917504);
    u16*      Gbf    = (u16*)     (ws + 1966080);
    u16*      Rbf    = (u16*)     (ws + 2097152);
    u16*      Rt     = (u16*)     (ws + 6291456);
    float*    Gp     = (float*)   (ws + 10485760);
    float*    emb    = (float*)   (ws + 14680064);
    float*    u      = (float*)   (ws + 23068672);

    k_norm<<<NROW/4, 256, 0, stream>>>(X, nrm0, fpart, gcnt);
    k_prep<<<256, 256, 0, stream>>>(X, nrm0, fpart, linear, dirv, feat,
                                    scal, f0, Rbf, Rt, cpart);
    k_gram<<<dim3(4,4,NZ), 256, 0, stream>>>(Rt, Gp, Gbf, cpart, cpart2, gcnt);
    k_apply<<<512, 256, 0, stream>>>(X, Rbf, Gbf, f0, cpart2, emb, nrm1,
                                     fpart1, cpart1, wpart1);
    k_sv<<<64, 256, 0, stream>>>(fpart1, scal, cpart1, wpart1, svec, scal2, vvec);
    k_uv<<<NROW/16, 256, 0, stream>>>(emb, nrm1, scal2, svec, u, vvec);
    k_out<<<NROW/16, 256, 0, stream>>>(emb, nrm1, scal2, vvec, u, out);
}

// Round 6
// 121.428 us; speedup vs baseline: 1.3313x; 1.3313x over previous
//
#include <hip/hip_runtime.h>
#include <math.h>

constexpr int NROW  = 8192;
constexpr int FD    = 256;
constexpr int NZ    = 16;
constexpr int RT_LD = NROW + 32;   // padded Rt row stride: breaks 16KB channel camping

typedef unsigned short u16;
typedef __attribute__((ext_vector_type(8))) short short8;   // bf16 x8 (4 VGPR)
typedef __attribute__((ext_vector_type(4))) float f32x4;    // acc

// ws layout (bytes):
//   0        scal[8]             (scal2 = 2 floats at +128)
//   4096     fpart[2048]         (8 KB)
//   12288    nrm0[8192]          (32 KB)
//   45056    nrm1[8192]          (32 KB)
//   77824    f0[8192]            (32 KB)
//   110592   fpart1[512]         (2 KB)
//   112640   svec[256]
//   113664   vvec[256]
//   114688   cpart2[16][256]     (16 KB)
//   131072   cpart[256][256]     (256 KB)
//   393216   cpart1[512][256]    (512 KB)
//   917504   wpart1[512][256]    (512 KB)
//   1441792  vpart[512][256]     (512 KB)
//   1966080  Gbf u16[256][256]   (128 KB)
//   2097152  Rbf u16[8192][256]  (4 MB)
//   6291456  Rt  u16[256][8224]  (4.02 MB)
//   10502144 Gp  f32[16][256][256] (4 MB)
//   14696448 emb f32[8192][256]  (8 MB)
//   23084928 u[8192]             (32 KB)

__device__ __forceinline__ float f_of(float nj, float A, float B, float AB) {
    float inner = AB * nj;
    return A - (inner <= 0.f ? inner : 0.f) * B;
}
__device__ __forceinline__ float wred(float s) {
    #pragma unroll
    for (int off = 32; off; off >>= 1) s += __shfl_xor(s, off);
    return s;
}
__device__ __forceinline__ float dot4(float4 a, float4 b) {
    return a.x*b.x + a.y*b.y + a.z*b.z + a.w*b.w;
}
__device__ __forceinline__ u16 f2bf(float x) {   // RNE fp32 -> bf16
    unsigned int u = __float_as_uint(x);
    u = (u + 0x7FFFu + ((u >> 16) & 1u)) >> 16;
    return (u16)u;
}

// one wave per row: nrm0[j] = ||row||^2 ; block partial -> fpart[2048]
__global__ void k_norm(const float* __restrict__ in, float* __restrict__ nrm,
                       float* __restrict__ fpart) {
    __shared__ float bs[4];
    int wave = threadIdx.x >> 6, lane = threadIdx.x & 63;
    int row = blockIdx.x * 4 + wave;
    const float4 v = *(const float4*)&in[(size_t)row * FD + lane * 4];
    float s = wred(dot4(v, v));
    if (lane == 0) { nrm[row] = s; bs[wave] = s; }
    __syncthreads();
    if (threadIdx.x == 0) fpart[blockIdx.x] = bs[0] + bs[1] + bs[2] + bs[3];
}

// prep: per-block scalar derivation, then R = f0*X bf16 row-major (Rbf) +
// transposed (Rt, padded stride) + colsum partials + f0 array. 256 blocks x 32 rows.
__global__ void __launch_bounds__(256, 2)
k_prep(const float* __restrict__ X, const float* __restrict__ nrm0,
       const float* __restrict__ fpart, const float* __restrict__ linear,
       const float* __restrict__ dirv, const float* __restrict__ feat,
       float* __restrict__ scal, float* __restrict__ f0,
       u16* __restrict__ Rbf, u16* __restrict__ Rt, float* __restrict__ cpart) {
    __shared__ u16 T[32][264];
    __shared__ float cred[4][256];
    __shared__ float l[256];
    __shared__ float ff[32];
    __shared__ float sdot[4];
    const int tid = threadIdx.x;
    const int r0 = blockIdx.x * 32;
    if (tid < 64) {
        for (int i = 0; i < 2; ++i) {
            float pa = 0.f, pb = 0.f;
            for (int k = tid; k < FD; k += 64) {
                float ll = linear[i*FD + k];
                pa += feat[i*FD + k] * ll;
                pb += dirv[i*FD + k] * ll;
            }
            pa = wred(pa); pb = wred(pb);
            if (tid == 0) { sdot[i] = pa; sdot[2 + i] = pb; }
        }
    }
    float s = 0.f;
    #pragma unroll
    for (int k = 0; k < 8; ++k) s += fpart[tid + k * 256];
    l[tid] = s;
    __syncthreads();
    for (int off = 128; off; off >>= 1) {
        if (tid < off) l[tid] += l[tid + off];
        __syncthreads();
    }
    const float F2 = l[0];
    const float a = sdot[0], b = sdot[2];
    const float sb = (b > 0.f) ? 1.f : ((b < 0.f) ? -1.f : 0.f);
    const float B = sb / sqrtf(F2);
    const float A = a, AB = a * B;
    if (blockIdx.x == 0 && tid == 0) {
        scal[0] = sdot[0]; scal[1] = sdot[1]; scal[2] = sdot[2]; scal[3] = sdot[3];
        scal[4] = A; scal[5] = B; scal[6] = AB; scal[7] = F2;
    }
    if (tid < 32) {
        float f = f_of(nrm0[r0 + tid], A, B, AB);
        ff[tid] = f;
        f0[r0 + tid] = f;
    }
    __syncthreads();
    const int cg0 = (tid & 63) * 4;
    const int rg = tid >> 6;
    float4 csum = make_float4(0.f, 0.f, 0.f, 0.f);
    #pragma unroll
    for (int i = 0; i < 8; ++i) {
        int row = rg * 8 + i;
        float4 v = *(const float4*)&X[(size_t)(r0 + row) * FD + cg0];
        float f = ff[row];
        v.x *= f; v.y *= f; v.z *= f; v.w *= f;
        csum.x += v.x; csum.y += v.y; csum.z += v.z; csum.w += v.w;
        unsigned lo = (unsigned)f2bf(v.x) | ((unsigned)f2bf(v.y) << 16);
        unsigned hi = (unsigned)f2bf(v.z) | ((unsigned)f2bf(v.w) << 16);
        uint2 pk = make_uint2(lo, hi);
        *(uint2*)&Rbf[(size_t)(r0 + row) * FD + cg0] = pk;
        *(uint2*)&T[row][cg0] = pk;
    }
    *(float4*)&cred[rg][cg0] = csum;
    __syncthreads();
    cpart[(size_t)blockIdx.x * FD + tid] =
        cred[0][tid] + cred[1][tid] + cred[2][tid] + cred[3][tid];
    const int c = tid;
    #pragma unroll
    for (int ch = 0; ch < 4; ++ch) {
        unsigned w0 = (unsigned)T[ch*8+0][c] | ((unsigned)T[ch*8+1][c] << 16);
        unsigned w1 = (unsigned)T[ch*8+2][c] | ((unsigned)T[ch*8+3][c] << 16);
        unsigned w2 = (unsigned)T[ch*8+4][c] | ((unsigned)T[ch*8+5][c] << 16);
        unsigned w3 = (unsigned)T[ch*8+6][c] | ((unsigned)T[ch*8+7][c] << 16);
        uint4 o = make_uint4(w0, w1, w2, w3);
        *(uint4*)&Rt[(size_t)c * RT_LD + r0 + ch * 8] = o;
    }
}

// Gram partials via MFMA (proven): grid (4,4,16); block = 4 waves, each a
// 32x32 quadrant (2x2 acc = 4 independent MFMA chains), K=512 per z.
__global__ void __launch_bounds__(256, 2)
k_gram(const u16* __restrict__ Rt, float* __restrict__ Gp) {
    const int bi = blockIdx.x, bj = blockIdx.y, z = blockIdx.z;
    const int tid = threadIdx.x, w = tid >> 6, lane = tid & 63;
    const int l15 = lane & 15, quad = lane >> 4;
    const int m0 = bi * 64 + (w & 1) * 32;
    const int n0 = bj * 64 + (w >> 1) * 32;
    const size_t kbase = (size_t)z * 512 + quad * 8;
    const u16* am0 = Rt + (size_t)(m0 + l15) * RT_LD + kbase;
    const u16* am1 = am0 + (size_t)16 * RT_LD;
    const u16* bn0 = Rt + (size_t)(n0 + l15) * RT_LD + kbase;
    const u16* bn1 = bn0 + (size_t)16 * RT_LD;
    f32x4 acc[2][2] = {};
    #pragma unroll
    for (int s = 0; s < 16; ++s) {
        int ko = s * 32;
        short8 a0 = *(const short8*)(am0 + ko);
        short8 a1 = *(const short8*)(am1 + ko);
        short8 b0 = *(const short8*)(bn0 + ko);
        short8 b1 = *(const short8*)(bn1 + ko);
        acc[0][0] = __builtin_amdgcn_mfma_f32_16x16x32_bf16(a0, b0, acc[0][0], 0, 0, 0);
        acc[0][1] = __builtin_amdgcn_mfma_f32_16x16x32_bf16(a0, b1, acc[0][1], 0, 0, 0);
        acc[1][0] = __builtin_amdgcn_mfma_f32_16x16x32_bf16(a1, b0, acc[1][0], 0, 0, 0);
        acc[1][1] = __builtin_amdgcn_mfma_f32_16x16x32_bf16(a1, b1, acc[1][1], 0, 0, 0);
    }
    float* gz = Gp + (size_t)z * (FD * FD);
    #pragma unroll
    for (int mi = 0; mi < 2; ++mi)
        #pragma unroll
        for (int ni = 0; ni < 2; ++ni)
            #pragma unroll
            for (int r = 0; r < 4; ++r)
                gz[(size_t)(m0 + mi*16 + quad*4 + r) * FD + n0 + ni*16 + l15] =
                    acc[mi][ni][r];
}

// Gbf = bf16(sum_z Gp); blocks 0..15 also fold cpart[256][256] -> cpart2[16][256]
__global__ void k_gred(const float* __restrict__ Gp, u16* __restrict__ Gbf,
                       const float* __restrict__ cpart, float* __restrict__ cpart2) {
    size_t e0 = (size_t)blockIdx.x * 256 + threadIdx.x;
    float s = 0.f;
    #pragma unroll
    for (int z = 0; z < NZ; ++z) s += Gp[(size_t)z * (FD * FD) + e0];
    Gbf[e0] = f2bf(s);
    if (blockIdx.x < 16) {
        float c = 0.f;
        #pragma unroll
        for (int k = 0; k < 16; ++k)
            c += cpart[(size_t)(blockIdx.x * 16 + k) * FD + threadIdx.x];
        cpart2[(size_t)blockIdx.x * FD + threadIdx.x] = c;
    }
}

// apply via MFMA; 512 blocks x 16 rows (2 blocks/CU). fp32 epilogue ->
// emb/nrm1/fpart1[512]/cpart1[512]/wpart1[512].
__global__ void __launch_bounds__(256, 2)
k_apply(const float* __restrict__ X, const u16* __restrict__ Rbf,
        const u16* __restrict__ Gbf, const float* __restrict__ f0,
        const float* __restrict__ cpart2, float* __restrict__ emb,
        float* __restrict__ nrm1, float* __restrict__ fpart1,
        float* __restrict__ cpart1, float* __restrict__ wpart1) {
    __shared__ float Sl[16][260];
    __shared__ float csh[FD];
    __shared__ float u0s[16], ffs[16], nrs[16];
    __shared__ float nw16[16][16];
    const int tid = threadIdx.x, w = tid >> 6, lane = tid & 63;
    const int l15 = lane & 15, quad = lane >> 4;
    const int r0 = blockIdx.x * 16;

    {
        float s = 0.f;
        #pragma unroll
        for (int g = 0; g < 16; ++g) s += cpart2[(size_t)g * FD + tid];
        csh[tid] = s;
    }
    if (tid < 16) ffs[tid] = f0[r0 + tid];
    __syncthreads();
    #pragma unroll
    for (int jj = 0; jj < 4; ++jj) {
        int row = w * 4 + jj;
        float4 xv = *(const float4*)&X[(size_t)(r0 + row) * FD + lane * 4];
        float4 cv = *(const float4*)&csh[lane * 4];
        float t = wred(dot4(xv, cv));
        if (lane == 0) u0s[row] = ffs[row] * t;
    }
    const u16* ap = Rbf + (size_t)(r0 + l15) * FD + quad * 8;
    const int n0w = w * 64;
    const u16* bp = Gbf + (size_t)(n0w + l15) * FD + quad * 8;
    f32x4 acc[4] = {};
    #pragma unroll
    for (int s = 0; s < 8; ++s) {
        int ko = s * 32;
        short8 a0 = *(const short8*)(ap + ko);
        short8 b0 = *(const short8*)(bp + ko);
        short8 b1 = *(const short8*)(bp + 16 * FD + ko);
        short8 b2 = *(const short8*)(bp + 32 * FD + ko);
        short8 b3 = *(const short8*)(bp + 48 * FD + ko);
        acc[0] = __builtin_amdgcn_mfma_f32_16x16x32_bf16(a0, b0, acc[0], 0, 0, 0);
        acc[1] = __builtin_amdgcn_mfma_f32_16x16x32_bf16(a0, b1, acc[1], 0, 0, 0);
        acc[2] = __builtin_amdgcn_mfma_f32_16x16x32_bf16(a0, b2, acc[2], 0, 0, 0);
        acc[3] = __builtin_amdgcn_mfma_f32_16x16x32_bf16(a0, b3, acc[3], 0, 0, 0);
    }
    #pragma unroll
    for (int ni = 0; ni < 4; ++ni)
        #pragma unroll
        for (int r = 0; r < 4; ++r)
            Sl[quad*4 + r][n0w + ni*16 + l15] = acc[ni][r];
    __syncthreads();
    const float invN = 1.0f / NROW;
    float er[16];
    float csum = 0.f;
    #pragma unroll
    for (int j = 0; j < 16; ++j) {
        float x = X[(size_t)(r0 + j) * FD + tid];
        float rv = ffs[j] * x;
        float e = rv + (Sl[j][tid] - u0s[j] * rv) * invN;
        emb[(size_t)(r0 + j) * FD + tid] = e;
        er[j] = e;
        csum += e;
        Sl[j][tid] = e * e;
    }
    __syncthreads();
    {
        int row = tid & 15, q = tid >> 4;
        float pn = 0.f;
        #pragma unroll
        for (int i = 0; i < 16; ++i) pn += Sl[row][q * 16 + i];
        nw16[row][q] = pn;
    }
    __syncthreads();
    if (tid < 16) {
        float nn = 0.f;
        #pragma unroll
        for (int q = 0; q < 16; ++q) nn += nw16[tid][q];
        nrm1[r0 + tid] = nn;
        nrs[tid] = nn;
    }
    __syncthreads();
    float wsum = 0.f;
    #pragma unroll
    for (int j = 0; j < 16; ++j) wsum += nrs[j] * er[j];
    cpart1[(size_t)blockIdx.x * FD + tid] = csum;
    wpart1[(size_t)blockIdx.x * FD + tid] = wsum;
    if (tid == 0) {
        float fp = 0.f;
        #pragma unroll
        for (int j = 0; j < 16; ++j) fp += nrs[j];
        fpart1[blockIdx.x] = fp;
    }
}

// depth-1 scalars from fpart1[512] (only k_sv needs the reduction now)
__device__ __forceinline__ void red1_scal(const float* fpart1, const float* scal,
                                          float* l, float& A, float& B, float& AB,
                                          float& kap) {
    int tid = threadIdx.x;
    l[tid] = fpart1[tid] + fpart1[tid + 256];
    __syncthreads();
    for (int off = 128; off; off >>= 1) {
        if (tid < off) l[tid] += l[tid + off];
        __syncthreads();
    }
    float F2 = l[0];
    float a = scal[1], b = scal[3];
    float sb = (b > 0.f) ? 1.f : ((b < 0.f) ? -1.f : 0.f);
    B = sb / sqrtf(F2);
    A = a; AB = a * B;
    kap = (AB <= 0.f) ? AB * B : 0.f;
    __syncthreads();
}

// svec[col] = A1 * sum_b cpart1[b][col] - kappa * sum_b wpart1[b][col]
// block 0 also publishes (A1, kap) to scal2 for the tail kernels.
__global__ void k_sv(const float* __restrict__ fpart1, const float* __restrict__ scal,
                     const float* __restrict__ cpart1, const float* __restrict__ wpart1,
                     float* __restrict__ svec, float* __restrict__ scal2) {
    __shared__ float l[256];
    float A1, B1, AB1, kap;
    red1_scal(fpart1, scal, l, A1, B1, AB1, kap);
    int tid = threadIdx.x;
    int col = blockIdx.x * 4 + (tid >> 6);
    int lane = tid & 63;
    float cs = 0.f, wsm = 0.f;
    #pragma unroll
    for (int b = lane; b < 512; b += 64) {
        cs  += cpart1[(size_t)b * FD + col];
        wsm += wpart1[(size_t)b * FD + col];
    }
    #pragma unroll
    for (int off = 32; off; off >>= 1) {
        cs  += __shfl_down(cs, off);
        wsm += __shfl_down(wsm, off);
    }
    if (lane == 0) svec[col] = A1 * cs - kap * wsm;
    if (blockIdx.x == 0 && tid == 0) { scal2[0] = A1; scal2[1] = kap; }
}

// u[row] = f1 (emb_row . s) ; vpart[bid][col] = sum_j (u_j f1_j) emb[j][col]
__global__ void k_uv(const float* __restrict__ emb, const float* __restrict__ nrm1,
                     const float* __restrict__ scal2, const float* __restrict__ svec,
                     float* __restrict__ u, float* __restrict__ vpart) {
    __shared__ float ssh[FD];
    __shared__ float uf[16];
    const int tid = threadIdx.x;
    const int r0 = blockIdx.x * 16;
    const float A1 = scal2[0], kap = scal2[1];
    ssh[tid] = svec[tid];
    __syncthreads();
    const int wave = tid >> 6, lane = tid & 63;
    float4 sv = *(const float4*)&ssh[lane*4];
    #pragma unroll
    for (int jj = 0; jj < 4; ++jj) {
        int row = r0 + wave * 4 + jj;
        float4 ev = *(const float4*)&emb[(size_t)row * FD + lane*4];
        float s = wred(dot4(ev, sv));
        if (lane == 0) {
            float f = A1 - kap * nrm1[row];
            float uj = f * s;
            u[row] = uj;
            uf[wave*4 + jj] = uj * f;
        }
    }
    __syncthreads();
    float vp = 0.f;
    #pragma unroll
    for (int j = 0; j < 16; ++j)
        vp += uf[j] * emb[(size_t)(r0 + j) * FD + tid];
    vpart[(size_t)blockIdx.x * FD + tid] = vp;
}

// reduce vpart[512][256] -> vvec[256] (deterministic order)
__global__ void k_vred(const float* __restrict__ part, float* __restrict__ vec) {
    int tid = threadIdx.x;
    int col = blockIdx.x * 4 + (tid >> 6);
    int lane = tid & 63;
    float s = 0.f;
    #pragma unroll
    for (int b = 0; b < 8; ++b) s += part[(size_t)(b * 64 + lane) * FD + col];
    #pragma unroll
    for (int off = 32; off; off >>= 1) s += __shfl_down(s, off);
    if (lane == 0) vec[col] = s;
}

// out[row] = (u + (f1*(emb_row . v) - u^2)/N)/N
__global__ void k_out(const float* __restrict__ emb, const float* __restrict__ nrm1,
                      const float* __restrict__ scal2, const float* __restrict__ vvec,
                      const float* __restrict__ u, float* __restrict__ out) {
    __shared__ float vsh[FD];
    const int tid = threadIdx.x;
    const int r0 = blockIdx.x * 16;
    const float A1 = scal2[0], kap = scal2[1];
    vsh[tid] = vvec[tid];
    __syncthreads();
    const int wave = tid >> 6, lane = tid & 63;
    const float invN = 1.0f / NROW;
    float4 vv = *(const float4*)&vsh[lane*4];
    #pragma unroll
    for (int jj = 0; jj < 4; ++jj) {
        int row = r0 + wave * 4 + jj;
        float4 ev = *(const float4*)&emb[(size_t)row * FD + lane*4];
        float s = wred(dot4(ev, vv));
        if (lane == 0 && row < NROW - 1) {
            float f = A1 - kap * nrm1[row];
            float uj = u[row];
            out[row] = (uj + (f * s - uj * uj) * invN) * invN;
        }
    }
}

extern "C" void kernel_launch(void* const* d_in, const int* in_sizes, int n_in,
                              void* d_out, int out_size, void* d_ws, size_t ws_size,
                              hipStream_t stream) {
    const float* X      = (const float*)d_in[0];
    // d_in[1] = coefs (unused by the reference forward)
    const float* linear = (const float*)d_in[2];
    const float* dirv   = (const float*)d_in[3];
    const float* feat   = (const float*)d_in[4];
    float* out = (float*)d_out;

    char* ws = (char*)d_ws;
    float* scal   = (float*)(ws + 0);
    float* scal2  = (float*)(ws + 128);
    float* fpart  = (float*)(ws + 4096);
    float* nrm0   = (float*)(ws + 12288);
    float* nrm1   = (float*)(ws + 45056);
    float* f0     = (float*)(ws + 77824);
    float* fpart1 = (float*)(ws + 110592);
    float* svec   = (float*)(ws + 112640);
    float* vvec   = (float*)(ws + 113664);
    float* cpart2 = (float*)(ws + 114688);
    float* cpart  = (float*)(ws + 131072);
    float* cpart1 = (float*)(ws + 393216);
    float* wpart1 = (float*)(ws + 917504);
    float* vpart  = (float*)(ws + 1441792);
    u16*   Gbf    = (u16*)  (ws + 1966080);
    u16*   Rbf    = (u16*)  (ws + 2097152);
    u16*   Rt     = (u16*)  (ws + 6291456);
    float* Gp     = (float*)(ws + 10502144);
    float* emb    = (float*)(ws + 14696448);
    float* u      = (float*)(ws + 23084928);

    k_norm<<<NROW/4, 256, 0, stream>>>(X, nrm0, fpart);
    k_prep<<<256, 256, 0, stream>>>(X, nrm0, fpart, linear, dirv, feat,
                                    scal, f0, Rbf, Rt, cpart);
    k_gram<<<dim3(4,4,NZ), 256, 0, stream>>>(Rt, Gp);
    k_gred<<<256, 256, 0, stream>>>(Gp, Gbf, cpart, cpart2);
    k_apply<<<512, 256, 0, stream>>>(X, Rbf, Gbf, f0, cpart2, emb, nrm1,
                                     fpart1, cpart1, wpart1);
    k_sv<<<64, 256, 0, stream>>>(fpart1, scal, cpart1, wpart1, svec, scal2);
    k_uv<<<NROW/16, 256, 0, stream>>>(emb, nrm1, scal2, svec, u, vpart);
    k_vred<<<64, 256, 0, stream>>>(vpart, vvec);
    k_out<<<NROW/16, 256, 0, stream>>>(emb, nrm1, scal2, vvec, u, out);
}